// Round 1
// 732.399 us; speedup vs baseline: 1.1607x; 1.1607x over previous
//
#include <hip/hip_runtime.h>
#include <hip/hip_bf16.h>
#include <math.h>

typedef __hip_bfloat16 bf16;
typedef __attribute__((ext_vector_type(8))) short bf16x8;
typedef __attribute__((ext_vector_type(4))) float f32x4;

static constexpr int DD = 1024;    // D
static constexpr int BB = 4;       // batch
static constexpr int SS = 4096;    // seq
static constexpr int FD = 4096;    // 4D
static constexpr int GDIM = 2048;  // 2D
static constexpr long SD = (long)SS * DD;   // per-batch x elements (4M)
static constexpr long SD4 = 4 * SD;         // per-batch ctx elements

// ---------------- async global->LDS (16B per lane) ----------------
__device__ __forceinline__ void gl2lds16(const bf16* g, bf16* l) {
    __builtin_amdgcn_global_load_lds(
        (const __attribute__((address_space(1))) void*)g,
        (__attribute__((address_space(3))) void*)l, 16, 0, 0);
}

// ================= 256x256 8-phase GEMM (m201-style schedule) =================
// C[M,N] = A[M,K] * BT[N,K]^T, bf16 in, z-batched via strides.
// BM=BN=256, BK=64, 512 threads = 8 waves (2Mx4N), per-wave output 128x64.
// LDS 128 KiB: A/B each [2 buf][2 kslice][256 rows][32 k] bf16 (16 KiB regions).
// Schedule: 4 phases per K-tile, phase=(mhalf, kslice):
//   {ds_read frags | stage 1 half-tile of tile t+1 into other buf | counted vmcnt
//    | s_barrier | lgkmcnt(0) | setprio(1) 16xMFMA setprio(0) | s_barrier}
// Stage order per tile: A.s0(P1) B.s0(P2) A.s1(P3) B.s1(P4); vmcnt(4) at P2/P4
// keeps exactly 2 half-tiles (4 wave-loads) in flight -> never drains to 0.
// LDS swizzle: chunk c (16B) at row r holds global chunk c ^ ((r>>1)&3); applied
// on the per-lane GLOBAL source (linear global_load_lds dest) and on ds_read.
// EPI 0: +bias[row], bf16    EPI 1: +bias[col], gelu, bf16    EPI 2: +bias[col]+X, f32
template <int EPI>
__global__ __launch_bounds__(512, 2) void gemm256(
    const bf16* __restrict__ A, const bf16* __restrict__ BT, void* __restrict__ Cp,
    const float* __restrict__ bias, const float* __restrict__ Xadd,
    int M, int N, int K, long strA, long strBT, long strC)
{
    extern __shared__ bf16 lds[];  // 65536 elems: A regions [0,32768), B [32768,65536)
    const int tid = threadIdx.x;
    const int l = tid & 63, wv = tid >> 6;
    const int wr = wv >> 2, wc = wv & 3;

    // T1: bijective XCD swizzle over the per-z 2D grid (nwg % 8 == 0 in all shapes)
    int lin = blockIdx.y * gridDim.x + blockIdx.x;
    {
        const int nwg = gridDim.x * gridDim.y;
        const int qq = nwg >> 3, rr = nwg & 7;
        const int xcd = lin & 7, idx = lin >> 3;
        lin = (xcd < rr ? xcd * (qq + 1) : rr * (qq + 1) + (xcd - rr) * qq) + idx;
    }
    const long m0 = (long)(lin / gridDim.x) * 256;
    const long n0 = (long)(lin % gridDim.x) * 256;

    A += (long)blockIdx.z * strA;
    BT += (long)blockIdx.z * strBT;

    // staging: thread t covers row (t>>2) [+128 for 2nd inst], 16B chunk (t&3),
    // source pre-swizzled: global chunk = (t&3) ^ s(row), s(row) = (row>>1)&3
    const int schunk = (tid & 3) ^ ((tid >> 3) & 3);
    const bf16* pa = A + (m0 + (tid >> 2)) * (long)K + schunk * 8;
    const bf16* pb = BT + (n0 + (tid >> 2)) * (long)K + schunk * 8;
    const long rowK = 128L * (long)K;
    const int stgOff = wv * 512;  // elements: wave-uniform 1 KiB slot

    // fragment read: lane (fm,q) reads row base+fm, chunk q ^ ((fm>>1)&3)
    const int fm = l & 15, q = l >> 4;
    const int lof = fm * 32 + ((q ^ ((fm >> 1) & 3)) * 8);  // elements

    f32x4 acc[8][4];
#pragma unroll
    for (int i = 0; i < 8; ++i)
#pragma unroll
        for (int j = 0; j < 4; ++j) acc[i][j] = (f32x4){0.f, 0.f, 0.f, 0.f};

    const int NT = K >> 6;

    // ---- prologue: tile 0 -> buf0, order A.s0 B.s0 A.s1 B.s1 (8 loads/wave)
    {
        bf16* dA0 = lds + stgOff;
        bf16* dB0 = lds + 32768 + stgOff;
        bf16* dA1 = lds + 8192 + stgOff;
        bf16* dB1 = lds + 40960 + stgOff;
        gl2lds16(pa, dA0);       gl2lds16(pa + rowK, dA0 + 4096);
        gl2lds16(pb, dB0);       gl2lds16(pb + rowK, dB0 + 4096);
        gl2lds16(pa + 32, dA1);  gl2lds16(pa + 32 + rowK, dA1 + 4096);
        gl2lds16(pb + 32, dB1);  gl2lds16(pb + 32 + rowK, dB1 + 4096);
        asm volatile("s_waitcnt vmcnt(4)" ::: "memory");  // s0 done, s1 in flight
        __builtin_amdgcn_s_barrier();
    }

    bf16x8 af[4], bq[4];
    for (int t = 0; t < NT; ++t) {
        const int buf = t & 1;
        const bool more = (t + 1) < NT;
        const long ko = (long)(t + 1) * 64;
        const bf16* As0 = lds + (buf << 1) * 8192;
        const bf16* As1 = As0 + 8192;
        const bf16* Bs0 = lds + 32768 + (buf << 1) * 8192;
        const bf16* Bs1 = Bs0 + 8192;
        bf16* nA0 = lds + ((buf ^ 1) << 1) * 8192 + stgOff;
        bf16* nA1 = nA0 + 8192;
        bf16* nB0 = lds + 32768 + ((buf ^ 1) << 1) * 8192 + stgOff;
        bf16* nB1 = nB0 + 8192;

        // -------- P1: (mh=0, ks=0) : read B.s0 + A.s0[mh0], stage A.s0(t+1)
        {
            const bf16* bb = Bs0 + (wc * 64) * 32 + lof;
            const bf16* ab = As0 + (wr * 128) * 32 + lof;
#pragma unroll
            for (int j = 0; j < 4; ++j) bq[j] = *(const bf16x8*)(bb + j * 512);
#pragma unroll
            for (int i = 0; i < 4; ++i) af[i] = *(const bf16x8*)(ab + i * 512);
            if (more) { gl2lds16(pa + ko, nA0); gl2lds16(pa + ko + rowK, nA0 + 4096); }
            __builtin_amdgcn_s_barrier();
            asm volatile("s_waitcnt lgkmcnt(0)" ::: "memory");
            __builtin_amdgcn_s_setprio(1);
#pragma unroll
            for (int i = 0; i < 4; ++i)
#pragma unroll
                for (int j = 0; j < 4; ++j)
                    acc[i][j] = __builtin_amdgcn_mfma_f32_16x16x32_bf16(af[i], bq[j], acc[i][j], 0, 0, 0);
            __builtin_amdgcn_s_setprio(0);
            __builtin_amdgcn_s_barrier();
        }
        // -------- P2: (mh=1, ks=0) : reuse bq, stage B.s0(t+1), wait for this tile's s1
        {
            const bf16* ab = As0 + (wr * 128 + 64) * 32 + lof;
#pragma unroll
            for (int i = 0; i < 4; ++i) af[i] = *(const bf16x8*)(ab + i * 512);
            if (more) {
                gl2lds16(pb + ko, nB0); gl2lds16(pb + ko + rowK, nB0 + 4096);
                asm volatile("s_waitcnt vmcnt(4)" ::: "memory");  // s1(t) done; P1/P2 stages in flight
            } else {
                asm volatile("s_waitcnt vmcnt(0)" ::: "memory");  // epilogue drain
            }
            __builtin_amdgcn_s_barrier();
            asm volatile("s_waitcnt lgkmcnt(0)" ::: "memory");
            __builtin_amdgcn_s_setprio(1);
#pragma unroll
            for (int i = 0; i < 4; ++i)
#pragma unroll
                for (int j = 0; j < 4; ++j)
                    acc[4 + i][j] = __builtin_amdgcn_mfma_f32_16x16x32_bf16(af[i], bq[j], acc[4 + i][j], 0, 0, 0);
            __builtin_amdgcn_s_setprio(0);
            __builtin_amdgcn_s_barrier();
        }
        // -------- P3: (mh=0, ks=1) : read B.s1 + A.s1[mh0], stage A.s1(t+1)
        {
            const bf16* bb = Bs1 + (wc * 64) * 32 + lof;
            const bf16* ab = As1 + (wr * 128) * 32 + lof;
#pragma unroll
            for (int j = 0; j < 4; ++j) bq[j] = *(const bf16x8*)(bb + j * 512);
#pragma unroll
            for (int i = 0; i < 4; ++i) af[i] = *(const bf16x8*)(ab + i * 512);
            if (more) { gl2lds16(pa + ko + 32, nA1); gl2lds16(pa + ko + 32 + rowK, nA1 + 4096); }
            __builtin_amdgcn_s_barrier();
            asm volatile("s_waitcnt lgkmcnt(0)" ::: "memory");
            __builtin_amdgcn_s_setprio(1);
#pragma unroll
            for (int i = 0; i < 4; ++i)
#pragma unroll
                for (int j = 0; j < 4; ++j)
                    acc[i][j] = __builtin_amdgcn_mfma_f32_16x16x32_bf16(af[i], bq[j], acc[i][j], 0, 0, 0);
            __builtin_amdgcn_s_setprio(0);
            __builtin_amdgcn_s_barrier();
        }
        // -------- P4: (mh=1, ks=1) : reuse bq, stage B.s1(t+1), wait for next tile's s0
        {
            const bf16* ab = As1 + (wr * 128 + 64) * 32 + lof;
#pragma unroll
            for (int i = 0; i < 4; ++i) af[i] = *(const bf16x8*)(ab + i * 512);
            if (more) {
                gl2lds16(pb + ko + 32, nB1); gl2lds16(pb + ko + 32 + rowK, nB1 + 4096);
                asm volatile("s_waitcnt vmcnt(4)" ::: "memory");  // s0(t+1) done; P3/P4 stages in flight
            }
            __builtin_amdgcn_s_barrier();
            asm volatile("s_waitcnt lgkmcnt(0)" ::: "memory");
            __builtin_amdgcn_s_setprio(1);
#pragma unroll
            for (int i = 0; i < 4; ++i)
#pragma unroll
                for (int j = 0; j < 4; ++j)
                    acc[4 + i][j] = __builtin_amdgcn_mfma_f32_16x16x32_bf16(af[i], bq[j], acc[4 + i][j], 0, 0, 0);
            __builtin_amdgcn_s_setprio(0);
            __builtin_amdgcn_s_barrier();
        }
    }

    // -------- epilogue --------
    const long cb = (long)blockIdx.z * strC;
#pragma unroll
    for (int i = 0; i < 8; ++i) {
        const long rB = m0 + wr * 128 + i * 16 + q * 4;
#pragma unroll
        for (int j = 0; j < 4; ++j) {
            const long col = n0 + wc * 64 + j * 16 + fm;
#pragma unroll
            for (int r2 = 0; r2 < 4; ++r2) {
                const long row = rB + r2;
                float v = acc[i][j][r2];
                if (EPI == 0) {
                    v += bias[row];
                    ((bf16*)Cp)[cb + row * (long)N + col] = __float2bfloat16(v);
                } else if (EPI == 1) {
                    v += bias[col];
                    v = 0.5f * v * (1.0f + erff(v * 0.70710678118654752f));
                    ((bf16*)Cp)[cb + row * (long)N + col] = __float2bfloat16(v);
                } else {
                    v += bias[col] + Xadd[row * (long)N + col];
                    ((float*)Cp)[cb + row * (long)N + col] = v;
                }
            }
        }
    }
}

// ---------------- fp32 -> bf16 straight convert ----------------
__global__ void conv_bf16(const float* __restrict__ in, bf16* __restrict__ out, long n) {
    long i = ((long)blockIdx.x * 256 + threadIdx.x) * 4;
    if (i >= n) return;
    const float4 v = *(const float4*)(in + i);
    bf16 o[4] = {__float2bfloat16(v.x), __float2bfloat16(v.y),
                 __float2bfloat16(v.z), __float2bfloat16(v.w)};
    *(uint2*)(out + i) = *(uint2*)o;
}

// ---------------- fp32 (R x C) -> bf16 (C x R) transpose, z-batched ----------------
__global__ void transpose_f32_bf16(const float* __restrict__ in, bf16* __restrict__ out,
                                   int R, int C, long inStr, long outStr) {
    __shared__ float tl[64][65];
    const float* ip = in + (long)blockIdx.z * inStr;
    bf16* op = out + (long)blockIdx.z * outStr;
    const int r0 = blockIdx.y * 64, c0 = blockIdx.x * 64;
    const int tr = threadIdx.x >> 6, tc = threadIdx.x & 63;
#pragma unroll
    for (int k = 0; k < 16; k++) {
        int r = k * 4 + tr;
        tl[r][tc] = ip[(long)(r0 + r) * C + c0 + tc];
    }
    __syncthreads();
#pragma unroll
    for (int k = 0; k < 16; k++) {
        int r = k * 4 + tr;
        op[(long)(c0 + r) * R + r0 + tc] = __float2bfloat16(tl[tc][r]);
    }
}

// ---------------- serial part: phase cumsum + complex memory, one wave per (z,d) ----------------
__global__ __launch_bounds__(256) void scan_kernel(
    const bf16* __restrict__ omegaT, const bf16* __restrict__ xT,
    const float* __restrict__ log_scale, bf16* __restrict__ ctx,
    long strIn, long strCtx)
{
    const int d = blockIdx.x * 4 + (threadIdx.x >> 6);
    const int lane = threadIdx.x & 63;
    const float sc = expf(log_scale[d]);
    const bf16* po = omegaT + (long)blockIdx.z * strIn + (long)d * SS;
    const bf16* px = xT + (long)blockIdx.z * strIn + (long)d * SS;
    bf16* pc = ctx + (long)blockIdx.z * strCtx + (long)d * SS;

    float phi_c = 0.f, mr_c = 0.f, mi_c = 0.f;
    for (int tchunk = 0; tchunk < SS / 64; tchunk++) {
        const int s = tchunk * 64 + lane;
        const float pos = (float)(s + 1);
        float w = __bfloat162float(po[s]) * sc * rsqrtf(pos);
#pragma unroll
        for (int dlt = 1; dlt < 64; dlt <<= 1) {
            float v = __shfl_up(w, dlt, 64);
            if (lane >= dlt) w += v;
        }
        const float phi = phi_c + w;
        float sph, cph;
        sincosf(phi, &sph, &cph);
        const float xv = __bfloat162float(px[s]);
        const float cr = xv * cph, ci = xv * sph;
        float crs = cr, cis = ci;
#pragma unroll
        for (int dlt = 1; dlt < 64; dlt <<= 1) {
            float v1 = __shfl_up(crs, dlt, 64);
            float v2 = __shfl_up(cis, dlt, 64);
            if (lane >= dlt) { crs += v1; cis += v2; }
        }
        const float invp = 1.0f / pos;
        const float mr = (mr_c + crs) * invp;
        const float mi = (mi_c + cis) * invp;
        const float rr = mr * cph + mi * sph;
        const float ri = mi * cph - mr * sph;
        pc[s] = __float2bfloat16(cr);
        pc[(long)DD * SS + s] = __float2bfloat16(ci);
        pc[2L * DD * SS + s] = __float2bfloat16(rr);
        pc[3L * DD * SS + s] = __float2bfloat16(ri);
        phi_c += __shfl(w, 63, 64);
        mr_c += __shfl(crs, 63, 64);
        mi_c += __shfl(cis, 63, 64);
    }
}

// ---------------- per-s LN stats over f (split-f + atomics), z-batched ----------------
__global__ void zero_f32(float* p, int n) {
    int i = blockIdx.x * 256 + threadIdx.x;
    if (i < n) p[i] = 0.f;
}

__global__ void stats_kernel(const bf16* __restrict__ ctx, float* __restrict__ sums,
                             float* __restrict__ sqs) {
    const int s = blockIdx.x * 256 + threadIdx.x;  // 0..S-1
    const int f0 = blockIdx.y * 512;
    const int z = blockIdx.z;
    const bf16* p = ctx + (long)z * SD4 + (long)f0 * SS + s;
    float sm = 0.f, sq = 0.f;
    for (int f = 0; f < 512; f++) {
        float v = __bfloat162float(p[(long)f * SS]);
        sm += v;
        sq += v * v;
    }
    atomicAdd(&sums[z * SS + s], sm);
    atomicAdd(&sqs[z * SS + s], sq);
}

// ---------------- in-place LayerNorm + transpose (f,s)->(s,f), triangular pairs ----------------
__global__ __launch_bounds__(256) void lnt_pair(
    bf16* __restrict__ ctx, const float* __restrict__ sums, const float* __restrict__ sqs,
    const float* __restrict__ gamma, const float* __restrict__ beta)
{
    __shared__ float tA[64][65];
    __shared__ float tB[64][65];
    const int z = blockIdx.z;
    int rem = blockIdx.x, a = 0;
    for (int i = 0; i < 64; i++) {
        int cnt = 64 - i;
        if (rem < cnt) { a = i; break; }
        rem -= cnt;
    }
    const int b = a + rem;
    bf16* base = ctx + (long)z * SD4;
    const int tr = threadIdx.x >> 6, tc = threadIdx.x & 63;
    const float* sums_z = sums + z * SS;
    const float* sqs_z = sqs + z * SS;

#pragma unroll
    for (int k = 0; k < 16; k++) {
        int i = k * 4 + tr;
        tA[i][tc] = __bfloat162float(base[(long)(a * 64 + i) * SS + b * 64 + tc]);
    }
    if (a != b) {
#pragma unroll
        for (int k = 0; k < 16; k++) {
            int i = k * 4 + tr;
            tB[i][tc] = __bfloat162float(base[(long)(b * 64 + i) * SS + a * 64 + tc]);
        }
    }
    __syncthreads();

    {
        const float g = gamma[a * 64 + tc], be = beta[a * 64 + tc];
#pragma unroll
        for (int k = 0; k < 16; k++) {
            const int i = k * 4 + tr;
            const int s = b * 64 + i;
            const float mu = sums_z[s] * (1.0f / FD);
            const float var = sqs_z[s] * (1.0f / FD) - mu * mu;
            const float is = rsqrtf(var + 1e-5f);
            const float v = (tA[tc][i] - mu) * is * g + be;
            base[(long)s * FD + a * 64 + tc] = __float2bfloat16(v);
        }
    }
    if (a != b) {
        const float g = gamma[b * 64 + tc], be = beta[b * 64 + tc];
#pragma unroll
        for (int k = 0; k < 16; k++) {
            const int i = k * 4 + tr;
            const int s = a * 64 + i;
            const float mu = sums_z[s] * (1.0f / FD);
            const float var = sqs_z[s] * (1.0f / FD) - mu * mu;
            const float is = rsqrtf(var + 1e-5f);
            const float v = (tB[tc][i] - mu) * is * g + be;
            base[(long)s * FD + b * 64 + tc] = __float2bfloat16(v);
        }
    }
}

// ---------------- launch ----------------
extern "C" void kernel_launch(void* const* d_in, const int* in_sizes, int n_in,
                              void* d_out, int out_size, void* d_ws, size_t ws_size,
                              hipStream_t stream)
{
    const float* x = (const float*)d_in[0];
    const float* Wo = (const float*)d_in[1];
    const float* bo = (const float*)d_in[2];
    const float* lsc = (const float*)d_in[3];
    const float* gam = (const float*)d_in[4];
    const float* bet = (const float*)d_in[5];
    const float* W1 = (const float*)d_in[6];
    const float* b1 = (const float*)d_in[7];
    const float* W2 = (const float*)d_in[8];
    const float* b2 = (const float*)d_in[9];

    // allow 128 KiB dynamic LDS for the 256^2 GEMM (once)
    static bool attr_done = false;
    if (!attr_done) {
        hipFuncSetAttribute(reinterpret_cast<const void*>(gemm256<0>),
                            hipFuncAttributeMaxDynamicSharedMemorySize, 131072);
        hipFuncSetAttribute(reinterpret_cast<const void*>(gemm256<1>),
                            hipFuncAttributeMaxDynamicSharedMemorySize, 131072);
        hipFuncSetAttribute(reinterpret_cast<const void*>(gemm256<2>),
                            hipFuncAttributeMaxDynamicSharedMemorySize, 131072);
        attr_done = true;
    }

    char* ws = (char*)d_ws;
    const size_t MB = 1024 * 1024;

    bf16* W1T = (bf16*)(ws + 0);           // 16 MB  (2048 x 4096)
    bf16* W2T = (bf16*)(ws + 16 * MB);     //  4 MB  (1024 x 2048)
    bf16* WoT = (bf16*)(ws + 20 * MB);     //  2 MB  (1024 x 1024)
    float* sums = (float*)(ws + 22 * MB);  // 4*SS floats
    float* sqs = sums + 4 * SS;

    transpose_f32_bf16<<<dim3(DD / 64, DD / 64, 1), 256, 0, stream>>>(Wo, WoT, DD, DD, 0, 0);
    transpose_f32_bf16<<<dim3(GDIM / 64, FD / 64, 1), 256, 0, stream>>>(W1, W1T, FD, GDIM, 0, 0);
    transpose_f32_bf16<<<dim3(DD / 64, GDIM / 64, 1), 256, 0, stream>>>(W2, W2T, GDIM, DD, 0, 0);

    const int NPAIR = 64 * 65 / 2;

    if (ws_size >= 220 * MB) {
        bf16* xT  = (bf16*)(ws + 23 * MB);
        bf16* omT = (bf16*)(ws + 55 * MB);
        bf16* ctx = (bf16*)(ws + 87 * MB);
        bf16* xb  = (bf16*)(ws + 87 * MB);
        bf16* h1  = (bf16*)(ws + 23 * MB);

        conv_bf16<<<(int)(BB * SD / 1024), 256, 0, stream>>>(x, xb, BB * SD);
        transpose_f32_bf16<<<dim3(DD / 64, SS / 64, BB), 256, 0, stream>>>(x, xT, SS, DD, SD, SD);

        // GEMM1 batched: omega^T[b] = Wo^T * x[b]^T   (M=1024, N=4096, K=1024)
        gemm256<0><<<dim3(SS / 256, DD / 256, BB), 512, 131072, stream>>>(
            WoT, xb, omT, bo, nullptr, DD, SS, DD, 0L, SD, SD);

        scan_kernel<<<dim3(DD / 4, 1, BB), 256, 0, stream>>>(omT, xT, lsc, ctx, SD, SD4);

        zero_f32<<<(8 * SS + 255) / 256, 256, 0, stream>>>(sums, 8 * SS);
        stats_kernel<<<dim3(SS / 256, FD / 512, BB), 256, 0, stream>>>(ctx, sums, sqs);

        lnt_pair<<<dim3(NPAIR, 1, BB), 256, 0, stream>>>(ctx, sums, sqs, gam, bet);

        // GEMM2 (M=16384, N=2048, K=4096): h1 = gelu(hln * W1 + b1)
        gemm256<1><<<dim3(GDIM / 256, BB * SS / 256, 1), 512, 131072, stream>>>(
            ctx, W1T, h1, b1, nullptr, BB * SS, GDIM, FD, 0L, 0L, 0L);

        // GEMM3 (M=16384, N=1024, K=2048): out = x + h1 * W2 + b2, fp32
        gemm256<2><<<dim3(DD / 256, BB * SS / 256, 1), 512, 131072, stream>>>(
            h1, W2T, d_out, b2, x, BB * SS, DD, GDIM, 0L, 0L, 0L);
    } else {
        bf16* xb  = (bf16*)(ws + 23 * MB);
        bf16* ctx = (bf16*)(ws + 23 * MB);
        bf16* omT = (bf16*)(ws + 55 * MB);
        bf16* xT  = (bf16*)(ws + 63 * MB);
        bf16* h1  = (bf16*)(ws + 55 * MB);

        for (int b = 0; b < BB; b++) {
            const float* xbf = x + (long)b * SD;
            conv_bf16<<<(int)(SD / 1024), 256, 0, stream>>>(xbf, xb, SD);
            transpose_f32_bf16<<<dim3(DD / 64, SS / 64, 1), 256, 0, stream>>>(xbf, xT, SS, DD, 0, 0);
            gemm256<0><<<dim3(SS / 256, DD / 256, 1), 512, 131072, stream>>>(
                WoT, xb, omT, bo, nullptr, DD, SS, DD, 0L, 0L, 0L);
            scan_kernel<<<dim3(DD / 4, 1, 1), 256, 0, stream>>>(omT, xT, lsc, ctx, 0L, 0L);
            zero_f32<<<(2 * SS + 255) / 256, 256, 0, stream>>>(sums, 2 * SS);
            stats_kernel<<<dim3(SS / 256, FD / 512, 1), 256, 0, stream>>>(ctx, sums, sqs);
            lnt_pair<<<dim3(NPAIR, 1, 1), 256, 0, stream>>>(ctx, sums, sqs, gam, bet);
            gemm256<1><<<dim3(GDIM / 256, SS / 256, 1), 512, 131072, stream>>>(
                ctx, W1T, h1, b1, nullptr, SS, GDIM, FD, 0L, 0L, 0L);
            gemm256<2><<<dim3(DD / 256, SS / 256, 1), 512, 131072, stream>>>(
                h1, W2T, (float*)d_out + (long)b * SD, b2, xbf, SS, DD, GDIM, 0L, 0L, 0L);
        }
    }
}